// Round 7
// baseline (268.900 us; speedup 1.0000x reference)
//
#include <hip/hip_runtime.h>
#include <hip/hip_bf16.h>
#include <stdint.h>

#define BATCH 16
#define CH    256
#define NSP   4096   // 64*64 spatial
#define NH    4
#define HD    64

typedef __attribute__((ext_vector_type(8))) short bf16x8;
typedef __attribute__((ext_vector_type(4))) float f32x4;
typedef __attribute__((ext_vector_type(4))) unsigned int u32x4;

// hardware RNE bf16 convert
__device__ __forceinline__ short f2bf(float f) {
    __hip_bfloat16 h = __float2bfloat16(f);
    union { __hip_bfloat16 h; short s; } u; u.h = h;
    return u.s;
}
__device__ __forceinline__ float bf2f(short s) {
    union { float f; unsigned u; } v; v.u = ((unsigned)(unsigned short)s) << 16;
    return v.f;
}

// ---------------- fused: GN stats (+ optional normalized-bf16 xn) + weight convert ----------------
// Stats blocks (0..511) each own exactly one (b,g): after stats, re-read the L2-hot
// 128KB slice and emit xn = (x-mu)*rstd*gamma+beta as bf16 (when XN=1).
template<int XN>
__global__ __launch_bounds__(256) void k_pre(
        const float* __restrict__ x, const float* __restrict__ wq, const float* __restrict__ wo,
        const float* __restrict__ gamma, const float* __restrict__ beta,
        float* __restrict__ mu, float* __restrict__ rstd,
        short* __restrict__ wq_bf, short* __restrict__ wo_bf, short* __restrict__ xn_bf) {
    int bg = blockIdx.x;
    if (bg < 512) {
        const float4* p = (const float4*)(x + (size_t)bg * 32768);
        float s = 0.f, sq = 0.f;
        for (int i = threadIdx.x; i < 8192; i += 256) {
            float4 v = p[i];
            s  += v.x + v.y + v.z + v.w;
            sq += v.x * v.x + v.y * v.y + v.z * v.z + v.w * v.w;
        }
        for (int off = 32; off; off >>= 1) { s += __shfl_down(s, off); sq += __shfl_down(sq, off); }
        __shared__ float ls[4], lq[4];
        __shared__ float sc8[8], sh8[8];
        int w = threadIdx.x >> 6;
        if ((threadIdx.x & 63) == 0) { ls[w] = s; lq[w] = sq; }
        __syncthreads();
        if (threadIdx.x == 0) {
            float S = ls[0] + ls[1] + ls[2] + ls[3];
            float Q = lq[0] + lq[1] + lq[2] + lq[3];
            float m = S / 32768.f;
            float var = Q / 32768.f - m * m;
            float r = rsqrtf(var + 1e-5f);
            mu[bg] = m; rstd[bg] = r;
            ls[0] = m; lq[0] = r;
        }
        if (XN) {
            __syncthreads();
            if (threadIdx.x < 8) {
                int g = bg & 31, c = g * 8 + threadIdx.x;
                float scv = lq[0] * gamma[c];
                sc8[threadIdx.x] = scv;
                sh8[threadIdx.x] = beta[c] - ls[0] * scv;
            }
            __syncthreads();
            short* dst = xn_bf + (size_t)bg * 32768;
            for (int i = threadIdx.x; i < 8192; i += 256) {
                float4 v = p[i];                 // L2-hot re-read
                int cl = i >> 10;                // channel-local 0..7
                float sc = sc8[cl], sh = sh8[cl];
                unsigned p0 = ((unsigned)(unsigned short)f2bf(v.x * sc + sh)) |
                              (((unsigned)(unsigned short)f2bf(v.y * sc + sh)) << 16);
                unsigned p1 = ((unsigned)(unsigned short)f2bf(v.z * sc + sh)) |
                              (((unsigned)(unsigned short)f2bf(v.w * sc + sh)) << 16);
                uint2 pk; pk.x = p0; pk.y = p1;
                *(uint2*)(dst + (size_t)i * 4) = pk;
            }
        }
    } else {
        int idx = ((bg - 512) * 256 + threadIdx.x) * 4;
        float4 v;
        short* dst;
        if (idx < 196608) { v = *(const float4*)(wq + idx); dst = wq_bf + idx; }
        else              { v = *(const float4*)(wo + (idx - 196608)); dst = wo_bf + (idx - 196608); }
        unsigned p0 = ((unsigned)(unsigned short)f2bf(v.x)) | (((unsigned)(unsigned short)f2bf(v.y)) << 16);
        unsigned p1 = ((unsigned)(unsigned short)f2bf(v.z)) | (((unsigned)(unsigned short)f2bf(v.w)) << 16);
        uint2 pk; pk.x = p0; pk.y = p1;
        *(uint2*)dst = pk;
    }
}

// ---------------- fused GN-apply + QKV + kv^T/ksum partials + q_t ----------------
// Proven R0 phase structure. USE_XN=1: B-build reads pre-normalized bf16 xn (half the
// bytes, no math, no scalar stat chain, L3-hot). USE_XN=0: exact R0 fp32 path.
template<int USE_XN>
__global__ __launch_bounds__(256) void k_gnqkv(
        const float* __restrict__ x, const float* __restrict__ gamma, const float* __restrict__ beta,
        const float* __restrict__ mu, const float* __restrict__ rstd,
        const short* __restrict__ xn_bf,
        const short* __restrict__ wq_bf, const float* __restrict__ b_qkv,
        short* __restrict__ q_t, short* __restrict__ kvp_bf, float* __restrict__ ksp) {
    int b = blockIdx.y, nt = blockIdx.x;
    int n0 = nt * 64;
    __shared__ short Blds[64 * 264];          // [n][c^swz]
    __shared__ union UR {
        struct { short kst[64 * 72]; short vst[64 * 72]; } s;
        short cst[64 * 136];
    } R;
    int t = threadIdx.x, lane = t & 63, wv = t >> 6, lr = lane & 15, quad = lane >> 4;

    // ---- build B tile ----
    if (USE_XN) {
        const short* xb = xn_bf + (size_t)b * CH * NSP + n0;
        int m = t & 15, cq = t >> 4;
        #pragma unroll 4
        for (int cb = 0; cb < 16; cb++) {
            int c = cb * 16 + cq;
            uint2 v = *(const uint2*)(xb + (size_t)c * NSP + m * 4);
            short sv[4];
            sv[0] = (short)(v.x & 0xffffu); sv[1] = (short)(v.x >> 16);
            sv[2] = (short)(v.y & 0xffffu); sv[3] = (short)(v.y >> 16);
            #pragma unroll
            for (int j = 0; j < 4; j++) {
                int n = m * 4 + j;
                int cc = c ^ (((n >> 4) & 3) << 3);
                Blds[n * 264 + cc] = sv[j];
            }
        }
    } else {
        const float* xb = x + (size_t)b * CH * NSP;
        int m = t & 15, cq = t >> 4;
        for (int cb = 0; cb < 16; cb++) {
            int c = cb * 16 + cq;
            int g = c >> 3;
            float sc = rstd[b * 32 + g] * gamma[c];
            float sh = beta[c] - mu[b * 32 + g] * sc;
            float4 v = *(const float4*)(xb + (size_t)c * NSP + n0 + m * 4);
            float vv[4] = {v.x, v.y, v.z, v.w};
            #pragma unroll
            for (int j = 0; j < 4; j++) {
                int n = m * 4 + j;
                int cc = c ^ (((n >> 4) & 3) << 3);
                Blds[n * 264 + cc] = f2bf(vv[j] * sc + sh);
            }
        }
    }
    __syncthreads();

    // ---- per-head k/v + kv partial ----
    for (int h = 0; h < 4; h++) {
        int base_row = (wv < 2 ? 256 : 512) + h * 64;   // k rows for waves 0-1, v rows for 2-3
        int sub = (wv & 1) * 32;
        f32x4 acc[2][4] = {};
        for (int k0 = 0; k0 < 256; k0 += 32) {          // barrier-free K-loop
            bf16x8 afr[2], bfr[4];
            #pragma unroll
            for (int mi = 0; mi < 2; mi++)
                afr[mi] = *(const bf16x8*)(wq_bf + (size_t)(base_row + sub + mi * 16 + lr) * 256 + k0 + quad * 8);
            #pragma unroll
            for (int ni = 0; ni < 4; ni++) {
                int rr = ni * 16 + lr;
                bfr[ni] = *(const bf16x8*)(Blds + rr * 264 + ((k0 + quad * 8) ^ (((rr >> 4) & 3) << 3)));
            }
            #pragma unroll
            for (int mi = 0; mi < 2; mi++)
                #pragma unroll
                for (int ni = 0; ni < 4; ni++)
                    acc[mi][ni] = __builtin_amdgcn_mfma_f32_16x16x32_bf16(afr[mi], bfr[ni], acc[mi][ni], 0, 0, 0);
        }
        __syncthreads();   // protect R reuse from previous pass
        short* dst = (wv < 2) ? R.s.kst : R.s.vst;
        bool is_k = (wv < 2);
        #pragma unroll
        for (int mi = 0; mi < 2; mi++)
          #pragma unroll
          for (int ni = 0; ni < 4; ni++)
            #pragma unroll
            for (int r = 0; r < 4; r++) {
                int ol = sub + mi * 16 + quad * 4 + r;   // 0..63
                int nl = ni * 16 + lr;
                float v = acc[mi][ni][r] + b_qkv[base_row + ol];
                if (is_k) v = v > 0.f ? v + 1.f : __expf(v);   // elu(k)+1
                dst[ol * 72 + nl] = f2bf(v);
            }
        __syncthreads();
        // ksum partial
        {
            int d = t >> 2, nq = (t & 3) * 16;
            float s = 0.f;
            #pragma unroll
            for (int j = 0; j < 16; j++) s += bf2f(R.s.kst[d * 72 + nq + j]);
            s += __shfl_down(s, 2);
            s += __shfl_down(s, 1);
            if ((t & 3) == 0) ksp[((size_t)(b * 4 + h) * 64 + nt) * 64 + d] = s;
        }
        // kv^T partial: A = vst (e rows), B = kst (d rows), K = 64 n
        f32x4 acc2[4] = {};
        #pragma unroll
        for (int kk = 0; kk < 64; kk += 32) {
            bf16x8 af = *(const bf16x8*)(R.s.vst + (wv * 16 + lr) * 72 + kk + quad * 8);
            bf16x8 bfk[4];
            #pragma unroll
            for (int ni = 0; ni < 4; ni++)
                bfk[ni] = *(const bf16x8*)(R.s.kst + (ni * 16 + lr) * 72 + kk + quad * 8);
            #pragma unroll
            for (int ni = 0; ni < 4; ni++)
                acc2[ni] = __builtin_amdgcn_mfma_f32_16x16x32_bf16(af, bfk[ni], acc2[ni], 0, 0, 0);
        }
        short* kvdst = kvp_bf + ((size_t)(b * 4 + h) * 64 + nt) * 4096;
        #pragma unroll
        for (int ni = 0; ni < 4; ni++)
            #pragma unroll
            for (int r = 0; r < 4; r++)
                kvdst[(wv * 16 + quad * 4 + r) * 64 + ni * 16 + lr] = f2bf(acc2[ni][r]);
    }

    // ---- q passes (128 rows each), barrier-free K-loop ----
    for (int mtq = 0; mtq < 2; mtq++) {
        f32x4 acc[2][4] = {};
        int wm = wv * 32;
        for (int k0 = 0; k0 < 256; k0 += 32) {
            bf16x8 afr[2], bfr[4];
            #pragma unroll
            for (int mi = 0; mi < 2; mi++)
                afr[mi] = *(const bf16x8*)(wq_bf + (size_t)(mtq * 128 + wm + mi * 16 + lr) * 256 + k0 + quad * 8);
            #pragma unroll
            for (int ni = 0; ni < 4; ni++) {
                int rr = ni * 16 + lr;
                bfr[ni] = *(const bf16x8*)(Blds + rr * 264 + ((k0 + quad * 8) ^ (((rr >> 4) & 3) << 3)));
            }
            #pragma unroll
            for (int mi = 0; mi < 2; mi++)
                #pragma unroll
                for (int ni = 0; ni < 4; ni++)
                    acc[mi][ni] = __builtin_amdgcn_mfma_f32_16x16x32_bf16(afr[mi], bfr[ni], acc[mi][ni], 0, 0, 0);
        }
        __syncthreads();   // protect cst reuse
        #pragma unroll
        for (int mi = 0; mi < 2; mi++)
          #pragma unroll
          for (int ni = 0; ni < 4; ni++)
            #pragma unroll
            for (int r = 0; r < 4; r++) {
                int ol = wm + mi * 16 + quad * 4 + r;    // 0..127
                int nl = ni * 16 + lr;
                float v = acc[mi][ni][r] + b_qkv[mtq * 128 + ol];
                v = v > 0.f ? v + 1.f : __expf(v);       // elu(q)+1
                R.cst[nl * 136 + ol] = f2bf(v);
            }
        __syncthreads();
        #pragma unroll
        for (int i = 0; i < 4; i++) {
            int ch = t + i * 256;
            int row = ch >> 4, o8 = (ch & 15) * 8;
            int hh = mtq * 2 + (o8 >> 6), d0 = o8 & 63;
            *(u32x4*)(q_t + ((size_t)(b * 4 + hh) * NSP + n0 + row) * HD + d0) =
                *(const u32x4*)(R.cst + row * 136 + o8);
        }
    }
}

// ---------------- reduce bf16 kv partials -> bf16 kvT; fp32 ksum ----------------
__global__ __launch_bounds__(256) void k_kv_reduce(
        const short* __restrict__ kvp_bf, const float* __restrict__ ksp,
        short* __restrict__ kvT_bf, float* __restrict__ ksum_g) {
    int p = blockIdx.x, bh = blockIdx.y;
    int t = threadIdx.x, lane = t & 63, grp = t >> 6;
    int chunk = p * 64 + lane;                 // 0..511, 8 elems each
    const short* base = kvp_bf + (size_t)bh * 64 * 4096 + chunk * 8;
    float s[8] = {};
    for (int ntc = grp * 16; ntc < grp * 16 + 16; ntc++) {
        bf16x8 v = *(const bf16x8*)(base + (size_t)ntc * 4096);
        #pragma unroll
        for (int j = 0; j < 8; j++) s[j] += bf2f(v[j]);
    }
    __shared__ float red[4][64][8];
    if (grp) {
        #pragma unroll
        for (int j = 0; j < 8; j++) red[grp][lane][j] = s[j];
    }
    __syncthreads();
    if (grp == 0) {
        bf16x8 rv;
        #pragma unroll
        for (int j = 0; j < 8; j++) {
            float v = s[j] + red[1][lane][j] + red[2][lane][j] + red[3][lane][j];
            rv[j] = f2bf(v);
        }
        *(bf16x8*)(kvT_bf + (size_t)bh * 4096 + chunk * 8) = rv;
    }
    if (p == 0) {   // block-uniform branch
        const float* kb = ksp + (size_t)bh * 64 * 64 + lane;
        float ss = 0.f;
        for (int ntc = grp * 16; ntc < grp * 16 + 16; ntc++) ss += kb[(size_t)ntc * 64];
        __syncthreads();
        red[grp][lane][0] = ss;
        __syncthreads();
        if (grp == 0) ksum_g[bh * 64 + lane] = ss + red[1][lane][0] + red[2][lane][0] + red[3][lane][0];
    }
}

// ---------------- fused attention + PER-HEAD out-projection + residual ----------------
// R6 per-head fusion (LDS 27.1KB) but launch_bounds(256,3): VGPR cap 170 (kernel needs
// ~135; R6's (256,4)=128-cap likely spilled to scratch). 3 blocks/CU via LDS regardless.
__global__ __launch_bounds__(256, 3) void k_attn_out(
        const short* __restrict__ q_t, const short* __restrict__ kvT_bf,
        const float* __restrict__ ksum_g, const short* __restrict__ wo_bf,
        const float* __restrict__ b_out, const float* __restrict__ x,
        float* __restrict__ out) {
    int b = blockIdx.y, nt = blockIdx.x;
    int n0 = nt * 64;
    __shared__ short ql[64 * 68];    // [n][d]
    __shared__ short kvl[64 * 68];   // [e][d]
    __shared__ short Bh[64 * 68];    // [n][e] this head's normalized attn output
    __shared__ float dnp[4][64];
    int t = threadIdx.x, lane = t & 63, wv = t >> 6, lr = lane & 15, quad = lane >> 4;

    f32x4 aco[4][4] = {};            // out rows wv*64+mi*16, cols nj*16 (held across heads)
    int r0 = wv * 64;

    #pragma unroll 1
    for (int h = 0; h < 4; h++) {
        int bh = b * 4 + h;
        #pragma unroll
        for (int i = 0; i < 2; i++) {
            int ch = t + i * 256;
            int row = ch >> 3, dc = (ch & 7) * 8;
            *(u32x4*)(ql + row * 68 + dc) =
                *(const u32x4*)(q_t + ((size_t)bh * NSP + n0 + row) * HD + dc);
            *(u32x4*)(kvl + row * 68 + dc) =
                *(const u32x4*)(kvT_bf + (size_t)bh * 4096 + row * 64 + dc);
        }
        __syncthreads();
        {   // denom partial: thread (n=t&63, d-range=wv*16), fully parallel
            int n = t & 63, q0 = wv * 16;
            const float* ks = ksum_g + bh * 64 + q0;
            float s = 0.f;
            #pragma unroll
            for (int j = 0; j < 16; j += 8) {
                bf16x8 qv = *(const bf16x8*)(ql + n * 68 + q0 + j);
                #pragma unroll
                for (int u = 0; u < 8; u++) s += bf2f(qv[u]) * ks[j + u];
            }
            dnp[wv][n] = s;
        }
        // attn MFMA: wave -> n rows wv*16, all 64 e
        f32x4 acc2[4] = {};
        int nr = wv * 16;
        #pragma unroll
        for (int kk = 0; kk < 64; kk += 32) {
            bf16x8 af = *(const bf16x8*)(ql + (nr + lr) * 68 + kk + quad * 8);
            bf16x8 bfr[4];
            #pragma unroll
            for (int ni = 0; ni < 4; ni++)
                bfr[ni] = *(const bf16x8*)(kvl + (ni * 16 + lr) * 68 + kk + quad * 8);
            #pragma unroll
            for (int ni = 0; ni < 4; ni++)
                acc2[ni] = __builtin_amdgcn_mfma_f32_16x16x32_bf16(af, bfr[ni], acc2[ni], 0, 0, 0);
        }
        __syncthreads();      // dnp complete; ql/kvl reads complete
        float dn[4];
        #pragma unroll
        for (int r = 0; r < 4; r++) {
            int n = nr + quad * 4 + r;
            dn[r] = 1.f / (dnp[0][n] + dnp[1][n] + dnp[2][n] + dnp[3][n] + 1e-6f);
        }
        #pragma unroll
        for (int ni = 0; ni < 4; ni++)
            #pragma unroll
            for (int r = 0; r < 4; r++) {
                int n = nr + quad * 4 + r;
                Bh[n * 68 + ni * 16 + lr] = f2bf(acc2[ni][r] * dn[r]);
            }
        __syncthreads();      // Bh ready for all waves
        // out-GEMM partial over this head's 64-wide e slice (A from L2, barrier-free)
        #pragma unroll
        for (int kk = 0; kk < 2; kk++) {
            bf16x8 A[4];
            #pragma unroll
            for (int mi = 0; mi < 4; mi++)
                A[mi] = *(const bf16x8*)(wo_bf + (size_t)(r0 + mi * 16 + lr) * 256 + h * 64 + kk * 32 + quad * 8);
            bf16x8 bfr[4];
            #pragma unroll
            for (int nj = 0; nj < 4; nj++)
                bfr[nj] = *(const bf16x8*)(Bh + (nj * 16 + lr) * 68 + kk * 32 + quad * 8);
            #pragma unroll
            for (int mi = 0; mi < 4; mi++)
                #pragma unroll
                for (int nj = 0; nj < 4; nj++)
                    aco[mi][nj] = __builtin_amdgcn_mfma_f32_16x16x32_bf16(A[mi], bfr[nj], aco[mi][nj], 0, 0, 0);
        }
        // no barrier: next stage writes ql/kvl (disjoint from Bh); Bh's next
        // overwrite is two barriers away, by which point these reads are drained.
    }

    #pragma unroll
    for (int mi = 0; mi < 4; mi++)
      #pragma unroll
      for (int nj = 0; nj < 4; nj++)
        #pragma unroll
        for (int r = 0; r < 4; r++) {
            int o = r0 + mi * 16 + quad * 4 + r;
            int nl = nj * 16 + lr;
            size_t idx = ((size_t)b * CH + o) * NSP + n0 + nl;
            out[idx] = aco[mi][nj][r] + b_out[o] + x[idx];
        }
}

extern "C" void kernel_launch(void* const* d_in, const int* in_sizes, int n_in,
                              void* d_out, int out_size, void* d_ws, size_t ws_size,
                              hipStream_t stream) {
    const float* x     = (const float*)d_in[0];
    const float* gamma = (const float*)d_in[1];
    const float* beta  = (const float*)d_in[2];
    const float* w_qkv = (const float*)d_in[3];
    const float* b_qkv = (const float*)d_in[4];
    const float* w_out = (const float*)d_in[5];
    const float* b_out = (const float*)d_in[6];
    float* out = (float*)d_out;

    char* ws = (char*)d_ws;
    size_t off = 0;
    float* mu     = (float*)(ws + off); off += 2048;
    float* rstd   = (float*)(ws + off); off += 2048;
    short* wq_bf  = (short*)(ws + off); off += (size_t)768 * 256 * 2;
    short* wo_bf  = (short*)(ws + off); off += (size_t)256 * 256 * 2;
    short* q_t    = (short*)(ws + off); off += (size_t)BATCH * NSP * CH * 2;   // [b][h][n][d]
    short* kvp_bf = (short*)(ws + off); off += (size_t)64 * 64 * 4096 * 2;     // [bh][nt64][e][d] bf16
    float* ksp    = (float*)(ws + off); off += (size_t)64 * 64 * 64 * 4;       // [bh][nt64][d]
    short* kvT_bf = (short*)(ws + off); off += (size_t)64 * 4096 * 2;          // [bh][e][d] bf16
    float* ksum_g = (float*)(ws + off); off += (size_t)64 * 64 * 4;            // [bh][d]
    size_t off_base = off;
    short* xn_bf  = (short*)(ws + off); off += (size_t)BATCH * CH * NSP * 2;   // [b][c][n] bf16 (optional)

    if (ws_size < off_base) return;
    bool use_xn = (ws_size >= off);

    if (use_xn) {
        k_pre<1><<<768, 256, 0, stream>>>(x, w_qkv, w_out, gamma, beta, mu, rstd, wq_bf, wo_bf, xn_bf);
        k_gnqkv<1><<<dim3(64, 16), 256, 0, stream>>>(x, gamma, beta, mu, rstd, xn_bf, wq_bf, b_qkv, q_t, kvp_bf, ksp);
    } else {
        k_pre<0><<<768, 256, 0, stream>>>(x, w_qkv, w_out, gamma, beta, mu, rstd, wq_bf, wo_bf, xn_bf);
        k_gnqkv<0><<<dim3(64, 16), 256, 0, stream>>>(x, gamma, beta, mu, rstd, xn_bf, wq_bf, b_qkv, q_t, kvp_bf, ksp);
    }
    k_kv_reduce<<<dim3(8, 64), 256, 0, stream>>>(kvp_bf, ksp, kvT_bf, ksum_g);
    k_attn_out<<<dim3(64, 16), 256, 0, stream>>>(q_t, kvT_bf, ksum_g, wo_bf, b_out, x, out);
}